// Round 12
// baseline (93.883 us; speedup 1.0000x reference)
//
#include <hip/hip_runtime.h>

#define H_ 512
#define N_ 32
#define B_ 4
#define L_ 2048
#define LC 64
#define NC 32   // L_/LC

typedef _Float16 f16x8 __attribute__((ext_vector_type(8)));
typedef float f32x4 __attribute__((ext_vector_type(4)));
typedef float f32x2 __attribute__((ext_vector_type(2)));

__device__ inline unsigned short f2h(float f) {
  _Float16 h = (_Float16)f;   // RNE
  return __builtin_bit_cast(unsigned short, h);
}

// ---- packed fp32 complex-step helpers (VOP3P, op_sel half-selects) ----
// A = {ar, ai}; X = {xr, xi}; B = {br, bi}; C = {cr, ci}.
// t1 = {br*u, bi*u}, u broadcast from uv.lo:
__device__ inline f32x2 pk_mul_bl(f32x2 b, f32x2 uv) {
  f32x2 d;
  asm("v_pk_mul_f32 %0, %1, %2 op_sel:[0,0] op_sel_hi:[1,0]"
      : "=v"(d) : "v"(b), "v"(uv));
  return d;
}
// same, u broadcast from uv.hi:
__device__ inline f32x2 pk_mul_bh(f32x2 b, f32x2 uv) {
  f32x2 d;
  asm("v_pk_mul_f32 %0, %1, %2 op_sel:[0,1] op_sel_hi:[1,1]"
      : "=v"(d) : "v"(b), "v"(uv));
  return d;
}
// cross: d = {-ai*xi + c.lo, ai*xr + c.hi}   (selects a.hi for both halves)
__device__ inline f32x2 pk_cross(f32x2 a, f32x2 x, f32x2 c) {
  f32x2 d;
  asm("v_pk_fma_f32 %0, %1, %2, %3 op_sel:[1,1,0] op_sel_hi:[1,0,1] neg_lo:[1,0,0]"
      : "=v"(d) : "v"(a), "v"(x), "v"(c));
  return d;
}
// real: d = {ar*xr + c.lo, ar*xi + c.hi}     (broadcasts a.lo)
__device__ inline f32x2 pk_real(f32x2 a, f32x2 x, f32x2 c) {
  f32x2 d;
  asm("v_pk_fma_f32 %0, %1, %2, %3 op_sel:[0,0,0] op_sel_hi:[0,1,1]"
      : "=v"(d) : "v"(a), "v"(x), "v"(c));
  return d;
}
// plain pk fma (projection accumulate)
__device__ inline f32x2 pk_fma(f32x2 a, f32x2 b, f32x2 c) {
  f32x2 d;
  asm("v_pk_fma_f32 %0, %1, %2, %3" : "=v"(d) : "v"(a), "v"(b), "v"(c));
  return d;
}

// ---- DPP cross-lane (quad_perm): xor1 = 0xB1, xor2 = 0x4E ----
__device__ inline float dpp_xor1(float x) {
  int r = __builtin_amdgcn_update_dpp(0, __builtin_bit_cast(int, x), 0xB1, 0xF, 0xF, true);
  return __builtin_bit_cast(float, r);
}
__device__ inline float dpp_xor2(float x) {
  int r = __builtin_amdgcn_update_dpp(0, __builtin_bit_cast(int, x), 0x4E, 0xF, 0xF, true);
  return __builtin_bit_cast(float, r);
}

#define GLD_LDS16(gsrc, ldst)                                                        \
  __builtin_amdgcn_global_load_lds(                                                  \
      (const __attribute__((address_space(1))) unsigned int*)(gsrc),                 \
      (__attribute__((address_space(3))) unsigned int*)(ldst), 16, 0, 0)

// lane ln owns n = ln*4..ln*4+3 of row h; packed pairs Ad2={ar,ai} Bd2={br,bi} Cc2={cr,ci}
#define DISCRETIZE_PK(h, ln)                                                         \
  {                                                                                  \
    float dtv = expf(log_dt[(h)]);                                                   \
    _Pragma("unroll")                                                                \
    for (int i = 0; i < 4; ++i) {                                                    \
      int n = (ln) * 4 + i;                                                          \
      int idx = ((h) << 5) + n;                                                      \
      float ar = -expf(log_A_real[idx]);                                             \
      float ai = A_imag[idx];                                                        \
      float dr = 0.5f * dtv * ar, di = 0.5f * dtv * ai;                              \
      float omr = 1.0f - dr;                                                         \
      float inv = 1.0f / (omr * omr + di * di);                                      \
      Ad2[i] = (f32x2){(1.0f - dr * dr - di * di) * inv, 2.0f * di * inv};           \
      float br = B_ri[2 * n], bi = B_ri[2 * n + 1];                                  \
      Bd2[i] = (f32x2){dtv * (br * omr - bi * di) * inv,                             \
                       dtv * (br * di + bi * omr) * inv};                            \
      float2 c = ((const float2*)C_ri)[idx];                                         \
      Cc2[i] = (f32x2){c.x, c.y};                                                    \
    }                                                                                \
  }

// stage u tile from x into ut[32 h][68 t] (transposed, padded)
#define STAGE_UT()                                                                   \
  {                                                                                  \
    int r = tid >> 3;                                                                \
    int q = tid & 7;                                                                 \
    _Pragma("unroll")                                                                \
    for (int i = 0; i < 2; ++i) {                                                    \
      int rr = r + 32 * i;                                                           \
      float4 vv = *(const float4*)(x + ((size_t)(b * L_ + c * LC + rr) * H_) +       \
                                   ht * 32 + q * 4);                                 \
      ut[q * 4 + 0][rr] = vv.x;                                                      \
      ut[q * 4 + 1][rr] = vv.y;                                                      \
      ut[q * 4 + 2][rr] = vv.z;                                                      \
      ut[q * 4 + 3][rr] = vv.w;                                                      \
    }                                                                                \
  }

// ---------------- scan1: W-transpose prologue + zero-init local chunk scans ----------------
// grid (NC-1, 16, B_) x 256 thr
__global__ __launch_bounds__(256, 8) void scan1_k(
    const float* __restrict__ x,
    const float* __restrict__ log_dt,
    const float* __restrict__ log_A_real,
    const float* __restrict__ A_imag,
    const float* __restrict__ B_ri,
    const float* __restrict__ C_ri,
    const float* __restrict__ W1,
    const float* __restrict__ W2,
    unsigned short* __restrict__ WT1,
    unsigned short* __restrict__ WT2,
    float2* __restrict__ xend) {
  __shared__ float ut[32][68];   // [h][t], 8704 B
  int c = blockIdx.x, ht = blockIdx.y, b = blockIdx.z;
  int tid = threadIdx.x;

  int flat = (b * 16 + ht) * (NC - 1) + c;   // 0..1983
  if (flat < 512) {
    float(*tile)[33] = (float(*)[33]) & ut[0][0];   // 4224 B scratch
    const float* W = (flat >> 8) ? W2 : W1;
    unsigned short* WT = (flat >> 8) ? WT2 : WT1;
    int rem = flat & 255;
    int k0 = (rem & 15) << 5, j0 = (rem >> 4) << 5;
    int tx = tid & 31, ty = tid >> 5;
#pragma unroll
    for (int i = 0; i < 32; i += 8)
      tile[ty + i][tx] = W[(size_t)(k0 + ty + i) * H_ + j0 + tx];
    __syncthreads();
#pragma unroll
    for (int i = 0; i < 32; i += 8)
      WT[(size_t)(j0 + ty + i) * H_ + k0 + tx] = f2h(tile[tx][ty + i]);
    __syncthreads();
  }

  STAGE_UT()

  int grp = tid >> 3, ln = tid & 7;
  int h = ht * 32 + grp, bh = b * H_ + h;
  f32x2 Ad2[4], Bd2[4], Cc2[4];
  DISCRETIZE_PK(h, ln)
  (void)Cc2;
  __syncthreads();   // ut ready

  f32x2 X[4] = {(f32x2){0.f, 0.f}, (f32x2){0.f, 0.f}, (f32x2){0.f, 0.f}, (f32x2){0.f, 0.f}};
#pragma unroll 4
  for (int t = 0; t < LC; t += 2) {
    f32x2 uv = *(const f32x2*)&ut[grp][t];
#pragma unroll
    for (int i = 0; i < 4; ++i) {
      f32x2 t1 = pk_mul_bl(Bd2[i], uv);
      X[i] = pk_real(Ad2[i], X[i], pk_cross(Ad2[i], X[i], t1));
    }
#pragma unroll
    for (int i = 0; i < 4; ++i) {
      f32x2 t1 = pk_mul_bh(Bd2[i], uv);
      X[i] = pk_real(Ad2[i], X[i], pk_cross(Ad2[i], X[i], t1));
    }
  }
  float2* dst = xend + ((size_t)bh * NC + c) * 32 + ln * 4;
#pragma unroll
  for (int i = 0; i < 4; ++i) dst[i] = make_float2(X[i].x, X[i].y);
}

// ---------------- scan2: lookback + full scan + DPP butterfly + scatter stores ----------------
// grid (NC, 16, B_) x 256 thr; no in-loop barriers.
__global__ __launch_bounds__(256, 8) void scan2_k(
    const float* __restrict__ x,
    const float* __restrict__ log_dt,
    const float* __restrict__ log_A_real,
    const float* __restrict__ A_imag,
    const float* __restrict__ B_ri,
    const float* __restrict__ C_ri,
    const float* __restrict__ Dv,
    const float2* __restrict__ xend,
    unsigned short* __restrict__ yN) {
  __shared__ float ut[32][68];
  int c = blockIdx.x, ht = blockIdx.y, b = blockIdx.z;
  int tid = threadIdx.x;

  STAGE_UT()

  int grp = tid >> 3, ln = tid & 7;
  int h = ht * 32 + grp, bh = b * H_ + h;
  f32x2 Ad2[4], Bd2[4], Cc2[4];
  DISCRETIZE_PK(h, ln)
  float dd = Dv[h];

  // Ad^64 by 6 squarings -> pair {pr, pi}
  f32x2 Ap2[4];
#pragma unroll
  for (int i = 0; i < 4; ++i) {
    float pr = Ad2[i].x, pi = Ad2[i].y;
#pragma unroll
    for (int s = 0; s < 6; ++s) {   // 2^6 = 64 = LC
      float qr = pr * pr - pi * pi;
      float qi = 2.0f * pr * pi;
      pr = qr; pi = qi;
    }
    Ap2[i] = (f32x2){pr, pi};
  }

  // lookback: Horner over xend[c'<c] with Ad^64
  f32x2 X[4] = {(f32x2){0.f, 0.f}, (f32x2){0.f, 0.f}, (f32x2){0.f, 0.f}, (f32x2){0.f, 0.f}};
  for (int cp = 0; cp < c; ++cp) {
    const float2* e = xend + ((size_t)bh * NC + cp) * 32 + ln * 4;
    float4 e01 = *(const float4*)e;
    float4 e23 = *(const float4*)(e + 2);
    f32x2 E[4] = {(f32x2){e01.x, e01.y}, (f32x2){e01.z, e01.w},
                  (f32x2){e23.x, e23.y}, (f32x2){e23.z, e23.w}};
#pragma unroll
    for (int i = 0; i < 4; ++i)
      X[i] = pk_real(Ap2[i], X[i], pk_cross(Ap2[i], X[i], E[i]));
  }
  __syncthreads();   // ut ready (only barrier)

  unsigned short* yb = yN + ((size_t)b * L_ + c * LC + ln) * H_ + h;

#pragma unroll
  for (int w = 0; w < 8; ++w) {
    float v[8];
#define STEP_BL(S, UV)                                                       \
    {                                                                        \
      f32x2 pacc = (f32x2){0.f, 0.f};                                        \
      _Pragma("unroll")                                                      \
      for (int i = 0; i < 4; ++i) {                                          \
        f32x2 t1 = pk_mul_bl(Bd2[i], UV);                                    \
        X[i] = pk_real(Ad2[i], X[i], pk_cross(Ad2[i], X[i], t1));            \
        pacc = pk_fma(Cc2[i], X[i], pacc);                                   \
      }                                                                      \
      v[(S)] = pacc.x - pacc.y;                                              \
    }
#define STEP_BH(S, UV)                                                       \
    {                                                                        \
      f32x2 pacc = (f32x2){0.f, 0.f};                                        \
      _Pragma("unroll")                                                      \
      for (int i = 0; i < 4; ++i) {                                          \
        f32x2 t1 = pk_mul_bh(Bd2[i], UV);                                    \
        X[i] = pk_real(Ad2[i], X[i], pk_cross(Ad2[i], X[i], t1));            \
        pacc = pk_fma(Cc2[i], X[i], pacc);                                   \
      }                                                                      \
      v[(S)] = pacc.x - pacc.y;                                              \
    }
    {
      f32x2 uv0 = *(const f32x2*)&ut[grp][w * 8 + 0];
      STEP_BL(0, uv0) STEP_BH(1, uv0)
      f32x2 uv1 = *(const f32x2*)&ut[grp][w * 8 + 2];
      STEP_BL(2, uv1) STEP_BH(3, uv1)
      f32x2 uv2 = *(const f32x2*)&ut[grp][w * 8 + 4];
      STEP_BL(4, uv2) STEP_BH(5, uv2)
      f32x2 uv3 = *(const f32x2*)&ut[grp][w * 8 + 6];
      STEP_BL(6, uv3) STEP_BH(7, uv3)
    }
    // reduce-scatter butterfly: stages 1,2 via DPP quad_perm, stage 4 via shfl
#define BFLY1(J)                                                             \
    {                                                                        \
      bool hi = (ln & 1) != 0;                                               \
      float snd = hi ? v[(J)] : v[(J) + 1];                                  \
      float rcv = dpp_xor1(snd);                                             \
      float kp = hi ? v[(J) + 1] : v[(J)];                                   \
      v[(J)] = kp + rcv;                                                     \
    }
#define BFLY2(J)                                                             \
    {                                                                        \
      bool hi = (ln & 2) != 0;                                               \
      float snd = hi ? v[(J)] : v[(J) + 2];                                  \
      float rcv = dpp_xor2(snd);                                             \
      float kp = hi ? v[(J) + 2] : v[(J)];                                   \
      v[(J)] = kp + rcv;                                                     \
    }
    BFLY1(0) BFLY1(2) BFLY1(4) BFLY1(6)
    BFLY2(0) BFLY2(4)
    {
      bool hi = (ln & 4) != 0;
      float snd = hi ? v[0] : v[4];
      float rcv = __shfl_xor(snd, 4);
      float kp = hi ? v[4] : v[0];
      v[0] = kp + rcv;
    }
    // lane ln holds sum_n Re(C x)[t0+ln]; add D*u once, store
    float ul = ut[grp][w * 8 + ln];
    yb[(size_t)(w * 8) * H_] = f2h(fmaf(dd, ul, v[0]));
  }
}

// ---------------- fused GLU GEMM (fp16 MFMA, single-buffer 32KB) ----------------
__global__ __launch_bounds__(256) void glu_gemm_k(const unsigned short* __restrict__ yN,
                                                  const unsigned short* __restrict__ WT1,
                                                  const unsigned short* __restrict__ WT2,
                                                  float* __restrict__ out) {
  __shared__ __align__(16) char lds[32768];   // A:16KB  B1:8KB  B2:8KB
  int tid = threadIdx.x;
  int m0 = blockIdx.x * 128;
  int n0 = blockIdx.y * 64;
  int wave = tid >> 6;
  int lane = tid & 63;
  int wm = wave >> 1;
  int wn = wave & 1;
  int srow = tid >> 3;          // 0..31
  int scb = (tid & 7) * 16;     // col-bytes within 128B row

  f32x4 acc1[4][2], acc2[4][2];
#pragma unroll
  for (int mf = 0; mf < 4; ++mf)
#pragma unroll
    for (int nf = 0; nf < 2; ++nf) {
      f32x4 z; z[0] = 0.f; z[1] = 0.f; z[2] = 0.f; z[3] = 0.f;
      acc1[mf][nf] = z; acc2[mf][nf] = z;
    }

  const char* ybase = (const char*)yN;
  const char* b1base = (const char*)WT1;
  const char* b2base = (const char*)WT2;
  char* As_ = lds;
  char* B1_ = lds + 16384;
  char* B2_ = lds + 24576;

  for (int k0 = 0; k0 < H_; k0 += 64) {
#pragma unroll
    for (int i = 0; i < 4; ++i) {
      int row = i * 32 + srow;
      int sc = scb ^ ((row & 7) << 4);
      GLD_LDS16(ybase + ((size_t)(m0 + row) * H_ + k0) * 2 + sc, As_ + wave * 1024 + i * 4096);
    }
#pragma unroll
    for (int i = 0; i < 2; ++i) {
      int row = i * 32 + srow;
      int sc = scb ^ ((row & 7) << 4);
      GLD_LDS16(b1base + ((size_t)(n0 + row) * H_ + k0) * 2 + sc, B1_ + wave * 1024 + i * 4096);
      GLD_LDS16(b2base + ((size_t)(n0 + row) * H_ + k0) * 2 + sc, B2_ + wave * 1024 + i * 4096);
    }
    __syncthreads();
#pragma unroll
    for (int ks = 0; ks < 2; ++ks) {
      f16x8 a[4], b1[2], b2[2];
      int kb = ks * 64 + (lane >> 4) * 16;
#pragma unroll
      for (int mf = 0; mf < 4; ++mf) {
        int row = wm * 64 + mf * 16 + (lane & 15);
        a[mf] = *(const f16x8*)(As_ + row * 128 + (kb ^ ((row & 7) << 4)));
      }
#pragma unroll
      for (int nf = 0; nf < 2; ++nf) {
        int row = wn * 32 + nf * 16 + (lane & 15);
        int off = row * 128 + (kb ^ ((row & 7) << 4));
        b1[nf] = *(const f16x8*)(B1_ + off);
        b2[nf] = *(const f16x8*)(B2_ + off);
      }
#pragma unroll
      for (int mf = 0; mf < 4; ++mf)
#pragma unroll
        for (int nf = 0; nf < 2; ++nf) {
          acc1[mf][nf] = __builtin_amdgcn_mfma_f32_16x16x32_f16(a[mf], b1[nf], acc1[mf][nf], 0, 0, 0);
          acc2[mf][nf] = __builtin_amdgcn_mfma_f32_16x16x32_f16(a[mf], b2[nf], acc2[mf][nf], 0, 0, 0);
        }
    }
    __syncthreads();
  }
  int nb = n0 + wn * 32 + (lane & 15);
  int rbase = (lane >> 4) * 4;
#pragma unroll
  for (int mf = 0; mf < 4; ++mf)
#pragma unroll
    for (int nf = 0; nf < 2; ++nf)
#pragma unroll
      for (int r = 0; r < 4; ++r) {
        int m = m0 + wm * 64 + mf * 16 + rbase + r;
        float g1 = acc1[mf][nf][r];
        float g2 = acc2[mf][nf][r];
        out[(size_t)m * H_ + nb + nf * 16] = g1 / (1.0f + __expf(-g2));
      }
}

extern "C" void kernel_launch(void* const* d_in, const int* in_sizes, int n_in,
                              void* d_out, int out_size, void* d_ws, size_t ws_size,
                              hipStream_t stream) {
  (void)in_sizes; (void)n_in; (void)out_size; (void)ws_size;
  const float* x          = (const float*)d_in[0];
  const float* log_dt     = (const float*)d_in[1];
  const float* log_A_real = (const float*)d_in[2];
  const float* A_imag     = (const float*)d_in[3];
  const float* B_ri       = (const float*)d_in[4];
  const float* C_ri       = (const float*)d_in[5];
  const float* Dv         = (const float*)d_in[6];
  const float* W1         = (const float*)d_in[7];
  const float* W2         = (const float*)d_in[8];
  float* out = (float*)d_out;
  char* ws = (char*)d_ws;

  unsigned short* yN   = (unsigned short*)(ws);                       // 8 MiB
  float2*         xend = (float2*)(ws + (8u << 20));                  // 16 MiB (NC=32)
  unsigned short* WT1  = (unsigned short*)(ws + (24u << 20));         // 512 KiB
  unsigned short* WT2  = (unsigned short*)(ws + (24u << 20) + (512u << 10));

  scan1_k<<<dim3(NC - 1, 16, B_), 256, 0, stream>>>(
      x, log_dt, log_A_real, A_imag, B_ri, C_ri, W1, W2, WT1, WT2, xend);

  scan2_k<<<dim3(NC, 16, B_), 256, 0, stream>>>(
      x, log_dt, log_A_real, A_imag, B_ri, C_ri, Dv, xend, yN);

  dim3 ggrid((B_ * L_) / 128, H_ / 64);
  glu_gemm_k<<<ggrid, 256, 0, stream>>>(yN, WT1, WT2, out);
}

// Round 13
// 79.562 us; speedup vs baseline: 1.1800x; 1.1800x over previous
//
#include <hip/hip_runtime.h>

#define H_ 512
#define N_ 32
#define B_ 4
#define L_ 2048
#define LC 128
#define NC 16   // L_/LC

typedef _Float16 f16x8 __attribute__((ext_vector_type(8)));
typedef float f32x4 __attribute__((ext_vector_type(4)));
typedef float f32x2 __attribute__((ext_vector_type(2)));

__device__ inline unsigned short f2h(float f) {
  _Float16 h = (_Float16)f;   // RNE
  return __builtin_bit_cast(unsigned short, h);
}

// ---- packed fp32 complex-step helpers (VOP3P, op_sel half-selects) ----
// t1 = {b.lo*u, b.hi*u}, u broadcast from uv.lo:
__device__ inline f32x2 pk_mul_bl(f32x2 b, f32x2 uv) {
  f32x2 d;
  asm("v_pk_mul_f32 %0, %1, %2 op_sel:[0,0] op_sel_hi:[1,0]"
      : "=v"(d) : "v"(b), "v"(uv));
  return d;
}
// cross: d = {-a.hi*x.hi + c.lo, a.hi*x.lo + c.hi}
__device__ inline f32x2 pk_cross(f32x2 a, f32x2 x, f32x2 c) {
  f32x2 d;
  asm("v_pk_fma_f32 %0, %1, %2, %3 op_sel:[1,1,0] op_sel_hi:[1,0,1] neg_lo:[1,0,0]"
      : "=v"(d) : "v"(a), "v"(x), "v"(c));
  return d;
}
// real: d = {a.lo*x.lo + c.lo, a.lo*x.hi + c.hi}
__device__ inline f32x2 pk_real(f32x2 a, f32x2 x, f32x2 c) {
  f32x2 d;
  asm("v_pk_fma_f32 %0, %1, %2, %3 op_sel:[0,0,0] op_sel_hi:[0,1,1]"
      : "=v"(d) : "v"(a), "v"(x), "v"(c));
  return d;
}

// ---- DPP cross-lane (quad_perm): xor1 = 0xB1, xor2 = 0x4E ----
__device__ inline float dpp_xor1(float x) {
  int r = __builtin_amdgcn_update_dpp(0, __builtin_bit_cast(int, x), 0xB1, 0xF, 0xF, true);
  return __builtin_bit_cast(float, r);
}
__device__ inline float dpp_xor2(float x) {
  int r = __builtin_amdgcn_update_dpp(0, __builtin_bit_cast(int, x), 0x4E, 0xF, 0xF, true);
  return __builtin_bit_cast(float, r);
}

#define GLD_LDS16(gsrc, ldst)                                                        \
  __builtin_amdgcn_global_load_lds(                                                  \
      (const __attribute__((address_space(1))) unsigned int*)(gsrc),                 \
      (__attribute__((address_space(3))) unsigned int*)(ldst), 16, 0, 0)

// lane ln (0..15) owns n = ln*2, ln*2+1 of row h.
// Ad2={ar,ai}  Bd2={br,bi}  Cc2={cr,ci}
#define DISCRETIZE2(h, ln)                                                           \
  {                                                                                  \
    float dtv = expf(log_dt[(h)]);                                                   \
    _Pragma("unroll")                                                                \
    for (int i = 0; i < 2; ++i) {                                                    \
      int n = (ln) * 2 + i;                                                          \
      int idx = ((h) << 5) + n;                                                      \
      float ar = -expf(log_A_real[idx]);                                             \
      float ai = A_imag[idx];                                                        \
      float dr = 0.5f * dtv * ar, di = 0.5f * dtv * ai;                              \
      float omr = 1.0f - dr;                                                         \
      float inv = 1.0f / (omr * omr + di * di);                                      \
      Ad2[i] = (f32x2){(1.0f - dr * dr - di * di) * inv, 2.0f * di * inv};           \
      float br = B_ri[2 * n], bi = B_ri[2 * n + 1];                                  \
      Bd2[i] = (f32x2){dtv * (br * omr - bi * di) * inv,                             \
                       dtv * (br * di + bi * omr) * inv};                            \
      float2 c = ((const float2*)C_ri)[idx];                                         \
      Cc2[i] = (f32x2){c.x, c.y};                                                    \
    }                                                                                \
  }

// stage u tile [128 t][16 h] (+pad 20), conflict-free float4 row writes
#define STAGE_UT16()                                                                 \
  {                                                                                  \
    int r = tid >> 2;                                                                \
    int q = tid & 3;                                                                 \
    _Pragma("unroll")                                                                \
    for (int i = 0; i < 2; ++i) {                                                    \
      int rr = r + 64 * i;                                                           \
      float4 vv = *(const float4*)(x + ((size_t)(b * L_ + c * LC + rr) * H_) +       \
                                   ht * 16 + q * 4);                                 \
      *(float4*)&ut[rr][q * 4] = vv;                                                 \
    }                                                                                \
  }

// ---------------- scan1: W-transpose prologue + zero-init local chunk scans ----------------
// grid (NC-1, 32, B_) x 256 thr. Block = (chunk c, 16-h tile ht, batch b).
__global__ __launch_bounds__(256, 8) void scan1_k(
    const float* __restrict__ x,
    const float* __restrict__ log_dt,
    const float* __restrict__ log_A_real,
    const float* __restrict__ A_imag,
    const float* __restrict__ B_ri,
    const float* __restrict__ C_ri,
    const float* __restrict__ W1,
    const float* __restrict__ W2,
    unsigned short* __restrict__ WT1,
    unsigned short* __restrict__ WT2,
    float2* __restrict__ xend) {
  __shared__ float ut[LC][20];   // 10240 B
  int c = blockIdx.x, ht = blockIdx.y, b = blockIdx.z;
  int tid = threadIdx.x;

  int flat = (b * 32 + ht) * (NC - 1) + c;   // 0..1919
  if (flat < 512) {
    float(*tile)[33] = (float(*)[33]) & ut[0][0];   // 4224 B scratch
    const float* W = (flat >> 8) ? W2 : W1;
    unsigned short* WT = (flat >> 8) ? WT2 : WT1;
    int rem = flat & 255;
    int k0 = (rem & 15) << 5, j0 = (rem >> 4) << 5;
    int tx = tid & 31, ty = tid >> 5;
#pragma unroll
    for (int i = 0; i < 32; i += 8)
      tile[ty + i][tx] = W[(size_t)(k0 + ty + i) * H_ + j0 + tx];
    __syncthreads();
#pragma unroll
    for (int i = 0; i < 32; i += 8)
      WT[(size_t)(j0 + ty + i) * H_ + k0 + tx] = f2h(tile[tx][ty + i]);
    __syncthreads();
  }

  STAGE_UT16()

  int grp = tid >> 4, ln = tid & 15;
  int h = ht * 16 + grp, bh = b * H_ + h;
  f32x2 Ad2[2], Bd2[2], Cc2[2];
  DISCRETIZE2(h, ln)
  (void)Cc2;
  __syncthreads();   // ut ready

  // state-only local scan: X+ = Ad*X + Bd*u
  f32x2 X[2] = {(f32x2){0.f, 0.f}, (f32x2){0.f, 0.f}};
#pragma unroll 8
  for (int t = 0; t < LC; ++t) {
    f32x2 Uv;
    Uv.x = ut[t][grp];
#pragma unroll
    for (int i = 0; i < 2; ++i) {
      f32x2 t1 = pk_mul_bl(Bd2[i], Uv);
      X[i] = pk_real(Ad2[i], X[i], pk_cross(Ad2[i], X[i], t1));
    }
  }
  float2* dst = xend + ((size_t)bh * NC + c) * 32 + ln * 2;
  dst[0] = make_float2(X[0].x, X[0].y);
  dst[1] = make_float2(X[1].x, X[1].y);
}

// ---------------- scan2: lookback (X-space) + Z=C*X scan + 4-stage butterfly ----------------
// grid (NC, 32, B_) x 256 thr; 32 waves/CU resident; no in-loop barriers.
__global__ __launch_bounds__(256, 8) void scan2_k(
    const float* __restrict__ x,
    const float* __restrict__ log_dt,
    const float* __restrict__ log_A_real,
    const float* __restrict__ A_imag,
    const float* __restrict__ B_ri,
    const float* __restrict__ C_ri,
    const float* __restrict__ Dv,
    const float2* __restrict__ xend,
    unsigned short* __restrict__ yN) {
  __shared__ float ut[LC][20];
  int c = blockIdx.x, ht = blockIdx.y, b = blockIdx.z;
  int tid = threadIdx.x;

  STAGE_UT16()

  int grp = tid >> 4, ln = tid & 15;
  int h = ht * 16 + grp, bh = b * H_ + h;
  f32x2 Ad2[2], Bd2[2], Cc2[2];
  DISCRETIZE2(h, ln)
  float dd = Dv[h];

  // CBd = C * Bd (complex, scalar once)
  f32x2 CBd2[2];
#pragma unroll
  for (int i = 0; i < 2; ++i)
    CBd2[i] = (f32x2){Cc2[i].x * Bd2[i].x - Cc2[i].y * Bd2[i].y,
                      Cc2[i].x * Bd2[i].y + Cc2[i].y * Bd2[i].x};

  // Ad^128 by 7 squarings
  f32x2 Ap2[2];
#pragma unroll
  for (int i = 0; i < 2; ++i) {
    float pr = Ad2[i].x, pi = Ad2[i].y;
#pragma unroll
    for (int s = 0; s < 7; ++s) {
      float qr = pr * pr - pi * pi;
      float qi = 2.0f * pr * pi;
      pr = qr; pi = qi;
    }
    Ap2[i] = (f32x2){pr, pi};
  }

  // lookback: Horner over xend[c'<c] with Ad^128 (X-space)
  f32x2 X[2] = {(f32x2){0.f, 0.f}, (f32x2){0.f, 0.f}};
  for (int cp = 0; cp < c; ++cp) {
    const float2* e = xend + ((size_t)bh * NC + cp) * 32 + ln * 2;
    float4 e01 = *(const float4*)e;
    f32x2 E[2] = {(f32x2){e01.x, e01.y}, (f32x2){e01.z, e01.w}};
#pragma unroll
    for (int i = 0; i < 2; ++i)
      X[i] = pk_real(Ap2[i], X[i], pk_cross(Ap2[i], X[i], E[i]));
  }

  // Z0 = C * xstart
  f32x2 Z[2];
#pragma unroll
  for (int i = 0; i < 2; ++i) {
    f32x2 zero = (f32x2){0.f, 0.f};
    Z[i] = pk_real(Cc2[i], X[i], pk_cross(Cc2[i], X[i], zero));
  }
  __syncthreads();   // ut ready (only barrier)

  unsigned short* yb = yN + ((size_t)b * L_ + c * LC + ln) * H_ + h;

#pragma unroll
  for (int w = 0; w < 8; ++w) {
    float v[16];
#define ZSTEP(S)                                                             \
    {                                                                        \
      f32x2 Uv;                                                              \
      Uv.x = ut[w * 16 + (S)][grp];                                          \
      _Pragma("unroll")                                                      \
      for (int i = 0; i < 2; ++i) {                                          \
        f32x2 t1 = pk_mul_bl(CBd2[i], Uv);                                   \
        Z[i] = pk_real(Ad2[i], Z[i], pk_cross(Ad2[i], Z[i], t1));            \
      }                                                                      \
      v[(S)] = Z[0].x + Z[1].x;                                              \
    }
    ZSTEP(0) ZSTEP(1) ZSTEP(2) ZSTEP(3) ZSTEP(4) ZSTEP(5) ZSTEP(6) ZSTEP(7)
    ZSTEP(8) ZSTEP(9) ZSTEP(10) ZSTEP(11) ZSTEP(12) ZSTEP(13) ZSTEP(14) ZSTEP(15)
    // 4-stage reduce-scatter butterfly over 16 lanes (literal indices)
#define BFLY1(J)                                                             \
    {                                                                        \
      bool hi = (ln & 1) != 0;                                               \
      float snd = hi ? v[(J)] : v[(J) + 1];                                  \
      float rcv = dpp_xor1(snd);                                             \
      float kp = hi ? v[(J) + 1] : v[(J)];                                   \
      v[(J)] = kp + rcv;                                                     \
    }
#define BFLY2(J)                                                             \
    {                                                                        \
      bool hi = (ln & 2) != 0;                                               \
      float snd = hi ? v[(J)] : v[(J) + 2];                                  \
      float rcv = dpp_xor2(snd);                                             \
      float kp = hi ? v[(J) + 2] : v[(J)];                                   \
      v[(J)] = kp + rcv;                                                     \
    }
#define BFLY4(J)                                                             \
    {                                                                        \
      bool hi = (ln & 4) != 0;                                               \
      float snd = hi ? v[(J)] : v[(J) + 4];                                  \
      float rcv = __shfl_xor(snd, 4);                                        \
      float kp = hi ? v[(J) + 4] : v[(J)];                                   \
      v[(J)] = kp + rcv;                                                     \
    }
    BFLY1(0) BFLY1(2) BFLY1(4) BFLY1(6) BFLY1(8) BFLY1(10) BFLY1(12) BFLY1(14)
    BFLY2(0) BFLY2(4) BFLY2(8) BFLY2(12)
    BFLY4(0) BFLY4(8)
    {
      bool hi = (ln & 8) != 0;
      float snd = hi ? v[0] : v[8];
      float rcv = __shfl_xor(snd, 8);
      float kp = hi ? v[8] : v[0];
      v[0] = kp + rcv;
    }
    // lane ln holds sum_n Re(Z)[t0+ln]; add D*u, store
    float ul = ut[w * 16 + ln][grp];
    yb[(size_t)(w * 16) * H_] = f2h(fmaf(dd, ul, v[0]));
  }
}

// ---------------- fused GLU GEMM (fp16 MFMA, single-buffer 32KB) ----------------
__global__ __launch_bounds__(256) void glu_gemm_k(const unsigned short* __restrict__ yN,
                                                  const unsigned short* __restrict__ WT1,
                                                  const unsigned short* __restrict__ WT2,
                                                  float* __restrict__ out) {
  __shared__ __align__(16) char lds[32768];   // A:16KB  B1:8KB  B2:8KB
  int tid = threadIdx.x;
  int m0 = blockIdx.x * 128;
  int n0 = blockIdx.y * 64;
  int wave = tid >> 6;
  int lane = tid & 63;
  int wm = wave >> 1;
  int wn = wave & 1;
  int srow = tid >> 3;          // 0..31
  int scb = (tid & 7) * 16;     // col-bytes within 128B row

  f32x4 acc1[4][2], acc2[4][2];
#pragma unroll
  for (int mf = 0; mf < 4; ++mf)
#pragma unroll
    for (int nf = 0; nf < 2; ++nf) {
      f32x4 z; z[0] = 0.f; z[1] = 0.f; z[2] = 0.f; z[3] = 0.f;
      acc1[mf][nf] = z; acc2[mf][nf] = z;
    }

  const char* ybase = (const char*)yN;
  const char* b1base = (const char*)WT1;
  const char* b2base = (const char*)WT2;
  char* As_ = lds;
  char* B1_ = lds + 16384;
  char* B2_ = lds + 24576;

  for (int k0 = 0; k0 < H_; k0 += 64) {
#pragma unroll
    for (int i = 0; i < 4; ++i) {
      int row = i * 32 + srow;
      int sc = scb ^ ((row & 7) << 4);
      GLD_LDS16(ybase + ((size_t)(m0 + row) * H_ + k0) * 2 + sc, As_ + wave * 1024 + i * 4096);
    }
#pragma unroll
    for (int i = 0; i < 2; ++i) {
      int row = i * 32 + srow;
      int sc = scb ^ ((row & 7) << 4);
      GLD_LDS16(b1base + ((size_t)(n0 + row) * H_ + k0) * 2 + sc, B1_ + wave * 1024 + i * 4096);
      GLD_LDS16(b2base + ((size_t)(n0 + row) * H_ + k0) * 2 + sc, B2_ + wave * 1024 + i * 4096);
    }
    __syncthreads();
#pragma unroll
    for (int ks = 0; ks < 2; ++ks) {
      f16x8 a[4], b1[2], b2[2];
      int kb = ks * 64 + (lane >> 4) * 16;
#pragma unroll
      for (int mf = 0; mf < 4; ++mf) {
        int row = wm * 64 + mf * 16 + (lane & 15);
        a[mf] = *(const f16x8*)(As_ + row * 128 + (kb ^ ((row & 7) << 4)));
      }
#pragma unroll
      for (int nf = 0; nf < 2; ++nf) {
        int row = wn * 32 + nf * 16 + (lane & 15);
        int off = row * 128 + (kb ^ ((row & 7) << 4));
        b1[nf] = *(const f16x8*)(B1_ + off);
        b2[nf] = *(const f16x8*)(B2_ + off);
      }
#pragma unroll
      for (int mf = 0; mf < 4; ++mf)
#pragma unroll
        for (int nf = 0; nf < 2; ++nf) {
          acc1[mf][nf] = __builtin_amdgcn_mfma_f32_16x16x32_f16(a[mf], b1[nf], acc1[mf][nf], 0, 0, 0);
          acc2[mf][nf] = __builtin_amdgcn_mfma_f32_16x16x32_f16(a[mf], b2[nf], acc2[mf][nf], 0, 0, 0);
        }
    }
    __syncthreads();
  }
  int nb = n0 + wn * 32 + (lane & 15);
  int rbase = (lane >> 4) * 4;
#pragma unroll
  for (int mf = 0; mf < 4; ++mf)
#pragma unroll
    for (int nf = 0; nf < 2; ++nf)
#pragma unroll
      for (int r = 0; r < 4; ++r) {
        int m = m0 + wm * 64 + mf * 16 + rbase + r;
        float g1 = acc1[mf][nf][r];
        float g2 = acc2[mf][nf][r];
        out[(size_t)m * H_ + nb + nf * 16] = g1 / (1.0f + __expf(-g2));
      }
}

extern "C" void kernel_launch(void* const* d_in, const int* in_sizes, int n_in,
                              void* d_out, int out_size, void* d_ws, size_t ws_size,
                              hipStream_t stream) {
  (void)in_sizes; (void)n_in; (void)out_size; (void)ws_size;
  const float* x          = (const float*)d_in[0];
  const float* log_dt     = (const float*)d_in[1];
  const float* log_A_real = (const float*)d_in[2];
  const float* A_imag     = (const float*)d_in[3];
  const float* B_ri       = (const float*)d_in[4];
  const float* C_ri       = (const float*)d_in[5];
  const float* Dv         = (const float*)d_in[6];
  const float* W1         = (const float*)d_in[7];
  const float* W2         = (const float*)d_in[8];
  float* out = (float*)d_out;
  char* ws = (char*)d_ws;

  unsigned short* yN   = (unsigned short*)(ws);                       // 8 MiB
  float2*         xend = (float2*)(ws + (8u << 20));                  // 8 MiB
  unsigned short* WT1  = (unsigned short*)(ws + (16u << 20));         // 512 KiB
  unsigned short* WT2  = (unsigned short*)(ws + (16u << 20) + (512u << 10));

  scan1_k<<<dim3(NC - 1, 32, B_), 256, 0, stream>>>(
      x, log_dt, log_A_real, A_imag, B_ri, C_ri, W1, W2, WT1, WT2, xend);

  scan2_k<<<dim3(NC, 32, B_), 256, 0, stream>>>(
      x, log_dt, log_A_real, A_imag, B_ri, C_ri, Dv, xend, yN);

  dim3 ggrid((B_ * L_) / 128, H_ / 64);
  glu_gemm_k<<<ggrid, 256, 0, stream>>>(yN, WT1, WT2, out);
}

// Round 14
// 79.226 us; speedup vs baseline: 1.1850x; 1.0042x over previous
//
#include <hip/hip_runtime.h>

#define H_ 512
#define N_ 32
#define B_ 4
#define L_ 2048
#define LC 128
#define NC 16   // L_/LC

typedef _Float16 f16x8 __attribute__((ext_vector_type(8)));
typedef float f32x4 __attribute__((ext_vector_type(4)));
typedef float f32x2 __attribute__((ext_vector_type(2)));

__device__ inline unsigned short f2h(float f) {
  _Float16 h = (_Float16)f;   // RNE
  return __builtin_bit_cast(unsigned short, h);
}

// ---- packed fp32 complex-step helpers (VOP3P, op_sel half-selects) ----
// d = {b.lo*u.lo, b.hi*u.lo}
__device__ inline f32x2 pk_mul_bl(f32x2 b, f32x2 uv) {
  f32x2 d;
  asm("v_pk_mul_f32 %0, %1, %2 op_sel:[0,0] op_sel_hi:[1,0]"
      : "=v"(d) : "v"(b), "v"(uv));
  return d;
}
// d = {b.lo*u.hi, b.hi*u.hi}
__device__ inline f32x2 pk_mul_bh(f32x2 b, f32x2 uv) {
  f32x2 d;
  asm("v_pk_mul_f32 %0, %1, %2 op_sel:[0,1] op_sel_hi:[1,1]"
      : "=v"(d) : "v"(b), "v"(uv));
  return d;
}
// cross: d = {-a.hi*x.hi + c.lo, a.hi*x.lo + c.hi}
__device__ inline f32x2 pk_cross(f32x2 a, f32x2 x, f32x2 c) {
  f32x2 d;
  asm("v_pk_fma_f32 %0, %1, %2, %3 op_sel:[1,1,0] op_sel_hi:[1,0,1] neg_lo:[1,0,0]"
      : "=v"(d) : "v"(a), "v"(x), "v"(c));
  return d;
}
// real: d = {a.lo*x.lo + c.lo, a.lo*x.hi + c.hi}
__device__ inline f32x2 pk_real(f32x2 a, f32x2 x, f32x2 c) {
  f32x2 d;
  asm("v_pk_fma_f32 %0, %1, %2, %3 op_sel:[0,0,0] op_sel_hi:[0,1,1]"
      : "=v"(d) : "v"(a), "v"(x), "v"(c));
  return d;
}

// ---- DPP cross-lane (quad_perm): xor1 = 0xB1, xor2 = 0x4E ----
__device__ inline float dpp_xor1(float x) {
  int r = __builtin_amdgcn_update_dpp(0, __builtin_bit_cast(int, x), 0xB1, 0xF, 0xF, true);
  return __builtin_bit_cast(float, r);
}
__device__ inline float dpp_xor2(float x) {
  int r = __builtin_amdgcn_update_dpp(0, __builtin_bit_cast(int, x), 0x4E, 0xF, 0xF, true);
  return __builtin_bit_cast(float, r);
}

#define GLD_LDS16(gsrc, ldst)                                                        \
  __builtin_amdgcn_global_load_lds(                                                  \
      (const __attribute__((address_space(1))) unsigned int*)(gsrc),                 \
      (__attribute__((address_space(3))) unsigned int*)(ldst), 16, 0, 0)

// lane ln (0..15) owns n = ln*2, ln*2+1 of row h.
#define DISCRETIZE2(h, ln)                                                           \
  {                                                                                  \
    float dtv = expf(log_dt[(h)]);                                                   \
    _Pragma("unroll")                                                                \
    for (int i = 0; i < 2; ++i) {                                                    \
      int n = (ln) * 2 + i;                                                          \
      int idx = ((h) << 5) + n;                                                      \
      float ar = -expf(log_A_real[idx]);                                             \
      float ai = A_imag[idx];                                                        \
      float dr = 0.5f * dtv * ar, di = 0.5f * dtv * ai;                              \
      float omr = 1.0f - dr;                                                         \
      float inv = 1.0f / (omr * omr + di * di);                                      \
      Ad2[i] = (f32x2){(1.0f - dr * dr - di * di) * inv, 2.0f * di * inv};           \
      float br = B_ri[2 * n], bi = B_ri[2 * n + 1];                                  \
      Bd2[i] = (f32x2){dtv * (br * omr - bi * di) * inv,                             \
                       dtv * (br * di + bi * omr) * inv};                            \
      float2 c = ((const float2*)C_ri)[idx];                                         \
      Cc2[i] = (f32x2){c.x, c.y};                                                    \
    }                                                                                \
  }

// stage u tile into ut[16 h][132 t]: 4 scalar ds_writes per float4 (2-way conflict = free)
#define STAGE_UT16T()                                                                \
  {                                                                                  \
    int r = tid >> 2;                                                                \
    int q = tid & 3;                                                                 \
    _Pragma("unroll")                                                                \
    for (int i = 0; i < 2; ++i) {                                                    \
      int rr = r + 64 * i;                                                           \
      float4 vv = *(const float4*)(x + ((size_t)(b * L_ + c * LC + rr) * H_) +       \
                                   ht * 16 + q * 4);                                 \
      ut[q * 4 + 0][rr] = vv.x;                                                      \
      ut[q * 4 + 1][rr] = vv.y;                                                      \
      ut[q * 4 + 2][rr] = vv.z;                                                      \
      ut[q * 4 + 3][rr] = vv.w;                                                      \
    }                                                                                \
  }

// ---------------- scan1: W-transpose prologue + zero-init local chunk scans ----------------
// grid (NC-1, 32, B_) x 256 thr. Block = (chunk c, 16-h tile ht, batch b).
__global__ __launch_bounds__(256, 8) void scan1_k(
    const float* __restrict__ x,
    const float* __restrict__ log_dt,
    const float* __restrict__ log_A_real,
    const float* __restrict__ A_imag,
    const float* __restrict__ B_ri,
    const float* __restrict__ C_ri,
    const float* __restrict__ W1,
    const float* __restrict__ W2,
    unsigned short* __restrict__ WT1,
    unsigned short* __restrict__ WT2,
    float2* __restrict__ xend) {
  __shared__ float ut[16][132];   // 8448 B
  int c = blockIdx.x, ht = blockIdx.y, b = blockIdx.z;
  int tid = threadIdx.x;

  int flat = (b * 32 + ht) * (NC - 1) + c;   // 0..1919
  if (flat < 512) {
    float(*tile)[33] = (float(*)[33]) & ut[0][0];   // 4224 B scratch
    const float* W = (flat >> 8) ? W2 : W1;
    unsigned short* WT = (flat >> 8) ? WT2 : WT1;
    int rem = flat & 255;
    int k0 = (rem & 15) << 5, j0 = (rem >> 4) << 5;
    int tx = tid & 31, ty = tid >> 5;
#pragma unroll
    for (int i = 0; i < 32; i += 8)
      tile[ty + i][tx] = W[(size_t)(k0 + ty + i) * H_ + j0 + tx];
    __syncthreads();
#pragma unroll
    for (int i = 0; i < 32; i += 8)
      WT[(size_t)(j0 + ty + i) * H_ + k0 + tx] = f2h(tile[tx][ty + i]);
    __syncthreads();
  }

  STAGE_UT16T()

  int grp = tid >> 4, ln = tid & 15;
  int h = ht * 16 + grp, bh = b * H_ + h;
  f32x2 Ad2[2], Bd2[2], Cc2[2];
  DISCRETIZE2(h, ln)
  (void)Cc2;
  __syncthreads();   // ut ready

  // state-only local scan: X+ = Ad*X + Bd*u ; one b64 u-read per 2 steps
  f32x2 X[2] = {(f32x2){0.f, 0.f}, (f32x2){0.f, 0.f}};
#pragma unroll 8
  for (int t = 0; t < LC; t += 2) {
    f32x2 pv = *(const f32x2*)&ut[grp][t];
#pragma unroll
    for (int i = 0; i < 2; ++i) {
      f32x2 t1 = pk_mul_bl(Bd2[i], pv);
      X[i] = pk_real(Ad2[i], X[i], pk_cross(Ad2[i], X[i], t1));
    }
#pragma unroll
    for (int i = 0; i < 2; ++i) {
      f32x2 t1 = pk_mul_bh(Bd2[i], pv);
      X[i] = pk_real(Ad2[i], X[i], pk_cross(Ad2[i], X[i], t1));
    }
  }
  float2* dst = xend + ((size_t)bh * NC + c) * 32 + ln * 2;
  dst[0] = make_float2(X[0].x, X[0].y);
  dst[1] = make_float2(X[1].x, X[1].y);
}

// ---------------- scan2: prefetched lookback + Z=C*X scan + 4-stage butterfly ----------------
// grid (NC, 32, B_) x 256 thr; no in-loop barriers.
__global__ __launch_bounds__(256, 8) void scan2_k(
    const float* __restrict__ x,
    const float* __restrict__ log_dt,
    const float* __restrict__ log_A_real,
    const float* __restrict__ A_imag,
    const float* __restrict__ B_ri,
    const float* __restrict__ C_ri,
    const float* __restrict__ Dv,
    const float2* __restrict__ xend,
    unsigned short* __restrict__ yN) {
  __shared__ float ut[16][132];
  int c = blockIdx.x, ht = blockIdx.y, b = blockIdx.z;
  int tid = threadIdx.x;

  STAGE_UT16T()

  int grp = tid >> 4, ln = tid & 15;
  int h = ht * 16 + grp, bh = b * H_ + h;
  f32x2 Ad2[2], Bd2[2], Cc2[2];
  DISCRETIZE2(h, ln)
  float dd16 = Dv[h] * 0.0625f;   // D/16, exact

  // CBd = C * Bd (complex)
  f32x2 CBd2[2];
#pragma unroll
  for (int i = 0; i < 2; ++i)
    CBd2[i] = (f32x2){Cc2[i].x * Bd2[i].x - Cc2[i].y * Bd2[i].y,
                      Cc2[i].x * Bd2[i].y + Cc2[i].y * Bd2[i].x};

  // Ad^128 by 7 squarings
  f32x2 Ap2[2];
#pragma unroll
  for (int i = 0; i < 2; ++i) {
    float pr = Ad2[i].x, pi = Ad2[i].y;
#pragma unroll
    for (int s = 0; s < 7; ++s) {
      float qr = pr * pr - pi * pi;
      float qi = 2.0f * pr * pi;
      pr = qr; pi = qi;
    }
    Ap2[i] = (f32x2){pr, pi};
  }

  // lookback: Horner over xend[c'<c] with Ad^128, 1-ahead prefetch
  f32x2 X[2] = {(f32x2){0.f, 0.f}, (f32x2){0.f, 0.f}};
  if (c > 0) {
    const float4* e = (const float4*)(xend + (size_t)bh * NC * 32 + ln * 2);
    float4 Ecur = e[0];   // records are 32 float2 apart = 16 float4
    for (int cp = 0; cp < c; ++cp) {
      float4 Enext;
      if (cp + 1 < c) Enext = e[(cp + 1) * 16];
      f32x2 E0 = (f32x2){Ecur.x, Ecur.y};
      f32x2 E1 = (f32x2){Ecur.z, Ecur.w};
      X[0] = pk_real(Ap2[0], X[0], pk_cross(Ap2[0], X[0], E0));
      X[1] = pk_real(Ap2[1], X[1], pk_cross(Ap2[1], X[1], E1));
      Ecur = Enext;
    }
  }

  // Z0 = C * xstart
  f32x2 Z[2];
#pragma unroll
  for (int i = 0; i < 2; ++i) {
    f32x2 zero = (f32x2){0.f, 0.f};
    Z[i] = pk_real(Cc2[i], X[i], pk_cross(Cc2[i], X[i], zero));
  }
  __syncthreads();   // ut ready (only barrier)

  unsigned short* yb = yN + ((size_t)b * L_ + c * LC + ln) * H_ + h;

#pragma unroll
  for (int w = 0; w < 8; ++w) {
    float v[16];
    // 16 steps, one b64 u-read per 2 steps; D*u/16 folded per lane (butterfly sums x16)
#define ZSTEP2(S)                                                            \
    {                                                                        \
      f32x2 pv = *(const f32x2*)&ut[grp][w * 16 + (S)];                      \
      _Pragma("unroll")                                                      \
      for (int i = 0; i < 2; ++i) {                                          \
        f32x2 t1 = pk_mul_bl(CBd2[i], pv);                                   \
        Z[i] = pk_real(Ad2[i], Z[i], pk_cross(Ad2[i], Z[i], t1));            \
      }                                                                      \
      v[(S)] = fmaf(dd16, pv.x, Z[0].x + Z[1].x);                            \
      _Pragma("unroll")                                                      \
      for (int i = 0; i < 2; ++i) {                                          \
        f32x2 t1 = pk_mul_bh(CBd2[i], pv);                                   \
        Z[i] = pk_real(Ad2[i], Z[i], pk_cross(Ad2[i], Z[i], t1));            \
      }                                                                      \
      v[(S) + 1] = fmaf(dd16, pv.y, Z[0].x + Z[1].x);                        \
    }
    ZSTEP2(0) ZSTEP2(2) ZSTEP2(4) ZSTEP2(6)
    ZSTEP2(8) ZSTEP2(10) ZSTEP2(12) ZSTEP2(14)
    // 4-stage reduce-scatter butterfly over 16 lanes (literal indices)
#define BFLY1(J)                                                             \
    {                                                                        \
      bool hi = (ln & 1) != 0;                                               \
      float snd = hi ? v[(J)] : v[(J) + 1];                                  \
      float rcv = dpp_xor1(snd);                                             \
      float kp = hi ? v[(J) + 1] : v[(J)];                                   \
      v[(J)] = kp + rcv;                                                     \
    }
#define BFLY2(J)                                                             \
    {                                                                        \
      bool hi = (ln & 2) != 0;                                               \
      float snd = hi ? v[(J)] : v[(J) + 2];                                  \
      float rcv = dpp_xor2(snd);                                             \
      float kp = hi ? v[(J) + 2] : v[(J)];                                   \
      v[(J)] = kp + rcv;                                                     \
    }
#define BFLY4(J)                                                             \
    {                                                                        \
      bool hi = (ln & 4) != 0;                                               \
      float snd = hi ? v[(J)] : v[(J) + 4];                                  \
      float rcv = __shfl_xor(snd, 4);                                        \
      float kp = hi ? v[(J) + 4] : v[(J)];                                   \
      v[(J)] = kp + rcv;                                                     \
    }
    BFLY1(0) BFLY1(2) BFLY1(4) BFLY1(6) BFLY1(8) BFLY1(10) BFLY1(12) BFLY1(14)
    BFLY2(0) BFLY2(4) BFLY2(8) BFLY2(12)
    BFLY4(0) BFLY4(8)
    {
      bool hi = (ln & 8) != 0;
      float snd = hi ? v[0] : v[8];
      float rcv = __shfl_xor(snd, 8);
      float kp = hi ? v[8] : v[0];
      v[0] = kp + rcv;
    }
    // lane ln holds y[t0+ln] (D*u already folded); store
    yb[(size_t)(w * 16) * H_] = f2h(v[0]);
  }
}

// ---------------- fused GLU GEMM (fp16 MFMA, single-buffer 32KB) ----------------
__global__ __launch_bounds__(256) void glu_gemm_k(const unsigned short* __restrict__ yN,
                                                  const unsigned short* __restrict__ WT1,
                                                  const unsigned short* __restrict__ WT2,
                                                  float* __restrict__ out) {
  __shared__ __align__(16) char lds[32768];   // A:16KB  B1:8KB  B2:8KB
  int tid = threadIdx.x;
  int m0 = blockIdx.x * 128;
  int n0 = blockIdx.y * 64;
  int wave = tid >> 6;
  int lane = tid & 63;
  int wm = wave >> 1;
  int wn = wave & 1;
  int srow = tid >> 3;          // 0..31
  int scb = (tid & 7) * 16;     // col-bytes within 128B row

  f32x4 acc1[4][2], acc2[4][2];
#pragma unroll
  for (int mf = 0; mf < 4; ++mf)
#pragma unroll
    for (int nf = 0; nf < 2; ++nf) {
      f32x4 z; z[0] = 0.f; z[1] = 0.f; z[2] = 0.f; z[3] = 0.f;
      acc1[mf][nf] = z; acc2[mf][nf] = z;
    }

  const char* ybase = (const char*)yN;
  const char* b1base = (const char*)WT1;
  const char* b2base = (const char*)WT2;
  char* As_ = lds;
  char* B1_ = lds + 16384;
  char* B2_ = lds + 24576;

  for (int k0 = 0; k0 < H_; k0 += 64) {
#pragma unroll
    for (int i = 0; i < 4; ++i) {
      int row = i * 32 + srow;
      int sc = scb ^ ((row & 7) << 4);
      GLD_LDS16(ybase + ((size_t)(m0 + row) * H_ + k0) * 2 + sc, As_ + wave * 1024 + i * 4096);
    }
#pragma unroll
    for (int i = 0; i < 2; ++i) {
      int row = i * 32 + srow;
      int sc = scb ^ ((row & 7) << 4);
      GLD_LDS16(b1base + ((size_t)(n0 + row) * H_ + k0) * 2 + sc, B1_ + wave * 1024 + i * 4096);
      GLD_LDS16(b2base + ((size_t)(n0 + row) * H_ + k0) * 2 + sc, B2_ + wave * 1024 + i * 4096);
    }
    __syncthreads();
#pragma unroll
    for (int ks = 0; ks < 2; ++ks) {
      f16x8 a[4], b1[2], b2[2];
      int kb = ks * 64 + (lane >> 4) * 16;
#pragma unroll
      for (int mf = 0; mf < 4; ++mf) {
        int row = wm * 64 + mf * 16 + (lane & 15);
        a[mf] = *(const f16x8*)(As_ + row * 128 + (kb ^ ((row & 7) << 4)));
      }
#pragma unroll
      for (int nf = 0; nf < 2; ++nf) {
        int row = wn * 32 + nf * 16 + (lane & 15);
        int off = row * 128 + (kb ^ ((row & 7) << 4));
        b1[nf] = *(const f16x8*)(B1_ + off);
        b2[nf] = *(const f16x8*)(B2_ + off);
      }
#pragma unroll
      for (int mf = 0; mf < 4; ++mf)
#pragma unroll
        for (int nf = 0; nf < 2; ++nf) {
          acc1[mf][nf] = __builtin_amdgcn_mfma_f32_16x16x32_f16(a[mf], b1[nf], acc1[mf][nf], 0, 0, 0);
          acc2[mf][nf] = __builtin_amdgcn_mfma_f32_16x16x32_f16(a[mf], b2[nf], acc2[mf][nf], 0, 0, 0);
        }
    }
    __syncthreads();
  }
  int nb = n0 + wn * 32 + (lane & 15);
  int rbase = (lane >> 4) * 4;
#pragma unroll
  for (int mf = 0; mf < 4; ++mf)
#pragma unroll
    for (int nf = 0; nf < 2; ++nf)
#pragma unroll
      for (int r = 0; r < 4; ++r) {
        int m = m0 + wm * 64 + mf * 16 + rbase + r;
        float g1 = acc1[mf][nf][r];
        float g2 = acc2[mf][nf][r];
        out[(size_t)m * H_ + nb + nf * 16] = g1 / (1.0f + __expf(-g2));
      }
}

extern "C" void kernel_launch(void* const* d_in, const int* in_sizes, int n_in,
                              void* d_out, int out_size, void* d_ws, size_t ws_size,
                              hipStream_t stream) {
  (void)in_sizes; (void)n_in; (void)out_size; (void)ws_size;
  const float* x          = (const float*)d_in[0];
  const float* log_dt     = (const float*)d_in[1];
  const float* log_A_real = (const float*)d_in[2];
  const float* A_imag     = (const float*)d_in[3];
  const float* B_ri       = (const float*)d_in[4];
  const float* C_ri       = (const float*)d_in[5];
  const float* Dv         = (const float*)d_in[6];
  const float* W1         = (const float*)d_in[7];
  const float* W2         = (const float*)d_in[8];
  float* out = (float*)d_out;
  char* ws = (char*)d_ws;

  unsigned short* yN   = (unsigned short*)(ws);                       // 8 MiB
  float2*         xend = (float2*)(ws + (8u << 20));                  // 8 MiB
  unsigned short* WT1  = (unsigned short*)(ws + (16u << 20));         // 512 KiB
  unsigned short* WT2  = (unsigned short*)(ws + (16u << 20) + (512u << 10));

  scan1_k<<<dim3(NC - 1, 32, B_), 256, 0, stream>>>(
      x, log_dt, log_A_real, A_imag, B_ri, C_ri, W1, W2, WT1, WT2, xend);

  scan2_k<<<dim3(NC, 32, B_), 256, 0, stream>>>(
      x, log_dt, log_A_real, A_imag, B_ri, C_ri, Dv, xend, yN);

  dim3 ggrid((B_ * L_) / 128, H_ / 64);
  glu_gemm_k<<<ggrid, 256, 0, stream>>>(yN, WT1, WT2, out);
}